// Round 1
// baseline (1706.665 us; speedup 1.0000x reference)
//
#include <hip/hip_runtime.h>
#include <hip/hip_bf16.h>

typedef unsigned short u16;
typedef unsigned int u32;
typedef __attribute__((ext_vector_type(8))) short s16x8;
typedef __attribute__((ext_vector_type(4))) short s16x4;
typedef __attribute__((ext_vector_type(4))) float f32x4;

__device__ inline u16 f2bf(float x) {
    u32 u = __float_as_uint(x);
    u32 r = (u + 0x7fffu + ((u >> 16) & 1u)) >> 16;
    return (u16)r;
}
__device__ inline float bf2f(u16 u) {
    return __uint_as_float(((u32)u) << 16);
}

// ---- features f32 -> bf16, with zero sentinel row at index N ----
__global__ void k_feat2bf(const float* __restrict__ f, u16* __restrict__ o,
                          int total, int nvalid) {
    int i = (blockIdx.x * 256 + threadIdx.x) * 8;
    if (i >= total) return;
    s16x8 v;
#pragma unroll
    for (int j = 0; j < 8; ++j) {
        float x = (i + j < nvalid) ? f[i + j] : 0.f;
        v[j] = (short)f2bf(x);
    }
    *(s16x8*)(o + i) = v;
}

// ---- weight swizzle: W[9][cin][128] f32 -> MFMA-B fragment-packed bf16 ----
// frag index fr = (tap*KC + kc)*8 + ct ; within frag: lane l holds 8 contiguous
// bf16 at fr*512 + l*8, element j = B[kc*32 + (l>>4)*8 + j][ct*16 + (l&15)]
__global__ void k_swz(const float* __restrict__ W, u16* __restrict__ o, int cin) {
    int i = blockIdx.x * 256 + threadIdx.x;
    int total = 9 * cin * 128;
    if (i >= total) return;
    int j = i & 7;
    int l = (i >> 3) & 63;
    int fr = i >> 9;
    int ct = fr & 7;
    int rest = fr >> 3;
    int kcn = cin >> 5;
    int kc = rest % kcn;
    int t = rest / kcn;
    int kk = kc * 32 + (l >> 4) * 8 + j;
    int c = ct * 16 + (l & 15);
    o[i] = f2bf(W[(t * cin + kk) * 128 + c]);
}

// ---- gather-conv: 1 wave = 16 voxels x 128 cols, K = 9*CIN via 16x16x32 MFMA
// writes z = lrelu(conv) as bf16 [N][128], accumulates per-channel sum/sumsq.
template <int CIN>
__global__ __launch_bounds__(256) void k_conv(
    const u16* __restrict__ src,   // (N+1) x CIN bf16, row N = zeros
    const int* __restrict__ nbr,   // 9 x N, sentinel = N
    const u16* __restrict__ w,     // fragment-packed weights
    u16* __restrict__ zout,        // N x 128 bf16
    float* __restrict__ stats,     // [256]: sum[128], sumsq[128]
    int N) {
    constexpr int KC = CIN / 32;
    const int lane = threadIdx.x & 63;
    const int wv = threadIdx.x >> 6;
    const int base = blockIdx.x * 64 + wv * 16;
    const int am = lane & 15;
    const int grp = lane >> 4;

    int ridx[9];
    const int vi = base + am;
#pragma unroll
    for (int t = 0; t < 9; ++t)
        ridx[t] = (vi < N) ? nbr[t * N + vi] : N;

    f32x4 acc[8];
#pragma unroll
    for (int ct = 0; ct < 8; ++ct) acc[ct] = (f32x4){0.f, 0.f, 0.f, 0.f};

#pragma unroll
    for (int t = 0; t < 9; ++t) {
        const u16* sp = src + (size_t)ridx[t] * CIN + grp * 8;
#pragma unroll
        for (int kc = 0; kc < KC; ++kc) {
            s16x8 a = *(const s16x8*)(sp + kc * 32);
            const u16* wp = w + (size_t)((t * KC + kc) * 8) * 512 + lane * 8;
#pragma unroll
            for (int ct = 0; ct < 8; ++ct) {
                s16x8 b = *(const s16x8*)(wp + ct * 512);
                acc[ct] = __builtin_amdgcn_mfma_f32_16x16x32_bf16(a, b, acc[ct], 0, 0, 0);
            }
        }
    }

#pragma unroll
    for (int ct = 0; ct < 8; ++ct) {
        float s = 0.f, q = 0.f;
#pragma unroll
        for (int j = 0; j < 4; ++j) {
            float x = acc[ct][j];
            float z = (x > 0.f) ? x : 0.01f * x;
            int row = base + grp * 4 + j;
            if (row < N) zout[(size_t)row * 128 + ct * 16 + am] = f2bf(z);
            s += z;
            q += z * z;
        }
        s += __shfl_xor(s, 16);
        q += __shfl_xor(q, 16);
        s += __shfl_xor(s, 32);
        q += __shfl_xor(q, 32);
        if (lane < 16) {
            atomicAdd(stats + ct * 16 + am, s);
            atomicAdd(stats + 128 + ct * 16 + am, q);
        }
    }
}

// ---- finalize two BN stat sets -> per-channel scale/shift ----
__global__ void k_fin(const float* __restrict__ stats,
                      const float* __restrict__ g0, const float* __restrict__ b0,
                      const float* __restrict__ g1, const float* __restrict__ b1,
                      float* __restrict__ ss, int N) {
    int tid = threadIdx.x;
    int set = tid >> 7, c = tid & 127;
    const float* st = stats + set * 256;
    float invN = 1.f / (float)N;
    float m = st[c] * invN;
    float var = st[128 + c] * invN - m * m;
    const float* g = set ? g1 : g0;
    const float* b = set ? b1 : b0;
    float sc = g[c] * rsqrtf(var + 1e-5f);
    float sh = b[c] - m * sc;
    float* o = ss + set * 256;
    o[c] = sc;
    o[128 + c] = sh;
}

// ---- y = z*scale + shift (bf16 out, with zero sentinel row N) ----
__global__ void k_aff(const u16* __restrict__ z, const float* __restrict__ ss,
                      u16* __restrict__ y, int N) {
    int v = blockIdx.x * 256 + threadIdx.x;
    int total = (N + 1) * 16;
    if (v >= total) return;
    int row = v >> 4;
    int cb = (v & 15) * 8;
    s16x8 o;
    if (row < N) {
        s16x8 zi = *(const s16x8*)(z + (size_t)row * 128 + cb);
#pragma unroll
        for (int j = 0; j < 8; ++j) {
            float x = bf2f((u16)zi[j]);
            float r = x * ss[cb + j] + ss[128 + cb + j];
            o[j] = (short)f2bf(r);
        }
    } else {
        o = (s16x8){0, 0, 0, 0, 0, 0, 0, 0};
    }
    *(s16x8*)(y + (size_t)row * 128 + cb) = o;
}

// ---- out = bn(z3) + bn(z4), f32 ----
__global__ void k_final(const u16* __restrict__ z3, const u16* __restrict__ z4,
                        const float* __restrict__ ssA, const float* __restrict__ ssB,
                        float* __restrict__ out, int N) {
    int v = blockIdx.x * 256 + threadIdx.x;
    int total = N * 32;
    if (v >= total) return;
    int row = v >> 5;
    int cb = (v & 31) * 4;
    s16x4 a = *(const s16x4*)(z3 + (size_t)row * 128 + cb);
    s16x4 b = *(const s16x4*)(z4 + (size_t)row * 128 + cb);
    f32x4 o;
#pragma unroll
    for (int j = 0; j < 4; ++j) {
        int c = cb + j;
        o[j] = bf2f((u16)a[j]) * ssA[c] + ssA[128 + c] +
               bf2f((u16)b[j]) * ssB[c] + ssB[128 + c];
    }
    *(f32x4*)(out + (size_t)row * 128 + cb) = o;
}

extern "C" void kernel_launch(void* const* d_in, const int* in_sizes, int n_in,
                              void* d_out, int out_size, void* d_ws, size_t ws_size,
                              hipStream_t stream) {
    const float* feat = (const float*)d_in[0];
    const int* nbr31 = (const int*)d_in[1];
    const int* nbr13 = (const int*)d_in[2];
    const float* W1 = (const float*)d_in[3];
    const float* W12 = (const float*)d_in[4];
    const float* W2 = (const float*)d_in[5];
    const float* W3 = (const float*)d_in[6];
    const float* g0 = (const float*)d_in[7];
    const float* b0 = (const float*)d_in[8];
    const float* g02 = (const float*)d_in[9];
    const float* b02 = (const float*)d_in[10];
    const float* g1 = (const float*)d_in[11];
    const float* b1 = (const float*)d_in[12];
    const float* g2 = (const float*)d_in[13];
    const float* b2 = (const float*)d_in[14];
    float* out = (float*)d_out;
    const int N = in_sizes[0] / 64;  // 200000

    char* p = (char*)d_ws;
    auto alloc = [&](size_t bytes) {
        char* r = p;
        p += (bytes + 255) & ~(size_t)255;
        return r;
    };
    float* stats = (float*)alloc(4 * 256 * sizeof(float));
    float* ss = (float*)alloc(4 * 256 * sizeof(float));
    u16* featbf = (u16*)alloc((size_t)(N + 1) * 64 * 2);
    u16* w1 = (u16*)alloc((size_t)9 * 64 * 128 * 2);
    u16* w2 = (u16*)alloc((size_t)9 * 64 * 128 * 2);
    u16* w12 = (u16*)alloc((size_t)9 * 128 * 128 * 2);
    u16* w3 = (u16*)alloc((size_t)9 * 128 * 128 * 2);
    u16* zA = (u16*)alloc((size_t)N * 128 * 2);
    u16* zB = (u16*)alloc((size_t)N * 128 * 2);
    u16* y1 = (u16*)alloc((size_t)(N + 1) * 128 * 2);
    u16* y2 = (u16*)alloc((size_t)(N + 1) * 128 * 2);

    hipMemsetAsync(stats, 0, 4 * 256 * sizeof(float), stream);

    int totF = (N + 1) * 64;
    k_feat2bf<<<(totF / 8 + 255) / 256, 256, 0, stream>>>(feat, featbf, totF, N * 64);
    k_swz<<<(9 * 64 * 128 + 255) / 256, 256, 0, stream>>>(W1, w1, 64);
    k_swz<<<(9 * 64 * 128 + 255) / 256, 256, 0, stream>>>(W2, w2, 64);
    k_swz<<<(9 * 128 * 128 + 255) / 256, 256, 0, stream>>>(W12, w12, 128);
    k_swz<<<(9 * 128 * 128 + 255) / 256, 256, 0, stream>>>(W3, w3, 128);

    int nblk = (N + 63) / 64;
    // shortcut: conv(nbr31, W1) ; main: conv(nbr13, W2)
    k_conv<64><<<nblk, 256, 0, stream>>>(featbf, nbr31, w1, zA, stats + 0, N);
    k_conv<64><<<nblk, 256, 0, stream>>>(featbf, nbr13, w2, zB, stats + 256, N);
    k_fin<<<1, 256, 0, stream>>>(stats, g0, b0, g1, b1, ss, N);
    int ablk = ((N + 1) * 16 + 255) / 256;
    k_aff<<<ablk, 256, 0, stream>>>(zA, ss + 0, y1, N);
    k_aff<<<ablk, 256, 0, stream>>>(zB, ss + 256, y2, N);
    // second stage: conv(y1, nbr13, W12) ; conv(y2, nbr31, W3)
    k_conv<128><<<nblk, 256, 0, stream>>>(y1, nbr13, w12, zA, stats + 512, N);
    k_conv<128><<<nblk, 256, 0, stream>>>(y2, nbr31, w3, zB, stats + 768, N);
    k_fin<<<1, 256, 0, stream>>>(stats + 512, g02, b02, g2, b2, ss + 512, N);
    k_final<<<(N * 32 + 255) / 256, 256, 0, stream>>>(zA, zB, ss + 512, ss + 768, out, N);
}

// Round 2
// 1359.845 us; speedup vs baseline: 1.2550x; 1.2550x over previous
//
#include <hip/hip_runtime.h>
#include <hip/hip_bf16.h>

typedef unsigned short u16;
typedef unsigned int u32;
typedef __attribute__((ext_vector_type(8))) short s16x8;
typedef __attribute__((ext_vector_type(4))) short s16x4;
typedef __attribute__((ext_vector_type(4))) float f32x4;

__device__ inline u16 f2bf(float x) {
    u32 u = __float_as_uint(x);
    u32 r = (u + 0x7fffu + ((u >> 16) & 1u)) >> 16;
    return (u16)r;
}
__device__ inline float bf2f(u16 u) {
    return __uint_as_float(((u32)u) << 16);
}

// ---- features f32 -> bf16, with zero sentinel row at index N ----
__global__ void k_feat2bf(const float* __restrict__ f, u16* __restrict__ o,
                          int total, int nvalid) {
    int i = (blockIdx.x * 256 + threadIdx.x) * 8;
    if (i >= total) return;
    s16x8 v;
#pragma unroll
    for (int j = 0; j < 8; ++j) {
        float x = (i + j < nvalid) ? f[i + j] : 0.f;
        v[j] = (short)f2bf(x);
    }
    *(s16x8*)(o + i) = v;
}

// ---- weight swizzle: W[9][cin][128] f32 -> MFMA-B fragment-packed bf16 ----
// frag index fr = (tap*KC + kc)*8 + ct ; within frag: lane l holds 8 contiguous
// bf16 at fr*512 + l*8, element j = B[kc*32 + (l>>4)*8 + j][ct*16 + (l&15)]
__global__ void k_swz(const float* __restrict__ W, u16* __restrict__ o, int cin) {
    int i = blockIdx.x * 256 + threadIdx.x;
    int total = 9 * cin * 128;
    if (i >= total) return;
    int j = i & 7;
    int l = (i >> 3) & 63;
    int fr = i >> 9;
    int ct = fr & 7;
    int rest = fr >> 3;
    int kcn = cin >> 5;
    int kc = rest % kcn;
    int t = rest / kcn;
    int kk = kc * 32 + (l >> 4) * 8 + j;
    int c = ct * 16 + (l & 15);
    o[i] = f2bf(W[(t * cin + kk) * 128 + c]);
}

// ---- gather-conv: 1 wave = 32 voxels (2 row-groups) x 128 cols ----
// K = 9*CIN via 16x16x32 MFMA. Writes z = lrelu(conv) as bf16 [N][128],
// accumulates per-channel sum/sumsq into stats.
template <int CIN>
__global__ __launch_bounds__(256) void k_conv(
    const u16* __restrict__ src,   // (N+1) x CIN bf16, row N = zeros
    const int* __restrict__ nbr,   // 9 x N, sentinel = N
    const u16* __restrict__ w,     // fragment-packed weights
    u16* __restrict__ zout,        // N x 128 bf16
    float* __restrict__ stats,     // [256]: sum[128], sumsq[128]
    int N) {
    constexpr int KC = CIN / 32;
    const int lane = threadIdx.x & 63;
    const int wv = threadIdx.x >> 6;
    const int base = blockIdx.x * 128 + wv * 32;
    const int am = lane & 15;
    const int grp = lane >> 4;

    int ridx0[9], ridx1[9];
    {
        int vi0 = base + am;
        int vi1 = base + 16 + am;
#pragma unroll
        for (int t = 0; t < 9; ++t) {
            ridx0[t] = (vi0 < N) ? nbr[t * N + vi0] : N;
            ridx1[t] = (vi1 < N) ? nbr[t * N + vi1] : N;
        }
    }

    f32x4 acc0[8], acc1[8];
#pragma unroll
    for (int ct = 0; ct < 8; ++ct) {
        acc0[ct] = (f32x4){0.f, 0.f, 0.f, 0.f};
        acc1[ct] = (f32x4){0.f, 0.f, 0.f, 0.f};
    }

#pragma unroll
    for (int t = 0; t < 9; ++t) {
        const u16* sp0 = src + (size_t)ridx0[t] * CIN + grp * 8;
        const u16* sp1 = src + (size_t)ridx1[t] * CIN + grp * 8;
#pragma unroll
        for (int kc = 0; kc < KC; ++kc) {
            s16x8 a0 = *(const s16x8*)(sp0 + kc * 32);
            s16x8 a1 = *(const s16x8*)(sp1 + kc * 32);
            const u16* wp = w + (size_t)((t * KC + kc) * 8) * 512 + lane * 8;
#pragma unroll
            for (int ct = 0; ct < 8; ++ct) {
                s16x8 b = *(const s16x8*)(wp + ct * 512);
                acc0[ct] = __builtin_amdgcn_mfma_f32_16x16x32_bf16(a0, b, acc0[ct], 0, 0, 0);
                acc1[ct] = __builtin_amdgcn_mfma_f32_16x16x32_bf16(a1, b, acc1[ct], 0, 0, 0);
            }
        }
    }

#pragma unroll
    for (int ct = 0; ct < 8; ++ct) {
        float s = 0.f, q = 0.f;
#pragma unroll
        for (int j = 0; j < 4; ++j) {
            {
                float x = acc0[ct][j];
                float z = (x > 0.f) ? x : 0.01f * x;
                int row = base + grp * 4 + j;
                if (row < N) zout[(size_t)row * 128 + ct * 16 + am] = f2bf(z);
                s += z;
                q += z * z;
            }
            {
                float x = acc1[ct][j];
                float z = (x > 0.f) ? x : 0.01f * x;
                int row = base + 16 + grp * 4 + j;
                if (row < N) zout[(size_t)row * 128 + ct * 16 + am] = f2bf(z);
                s += z;
                q += z * z;
            }
        }
        s += __shfl_xor(s, 16);
        q += __shfl_xor(q, 16);
        s += __shfl_xor(s, 32);
        q += __shfl_xor(q, 32);
        if (lane < 16) {
            atomicAdd(stats + ct * 16 + am, s);
            atomicAdd(stats + 128 + ct * 16 + am, q);
        }
    }
}

// ---- finalize two BN stat sets -> per-channel scale/shift ----
__global__ void k_fin(const float* __restrict__ stats,
                      const float* __restrict__ g0, const float* __restrict__ b0,
                      const float* __restrict__ g1, const float* __restrict__ b1,
                      float* __restrict__ ss, int N) {
    int tid = threadIdx.x;
    int set = tid >> 7, c = tid & 127;
    const float* st = stats + set * 256;
    float invN = 1.f / (float)N;
    float m = st[c] * invN;
    float var = st[128 + c] * invN - m * m;
    const float* g = set ? g1 : g0;
    const float* b = set ? b1 : b0;
    float sc = g[c] * rsqrtf(var + 1e-5f);
    float sh = b[c] - m * sc;
    float* o = ss + set * 256;
    o[c] = sc;
    o[128 + c] = sh;
}

// ---- y = z*scale + shift (bf16 out, with zero sentinel row N) ----
__global__ void k_aff(const u16* __restrict__ z, const float* __restrict__ ss,
                      u16* __restrict__ y, int N) {
    int v = blockIdx.x * 256 + threadIdx.x;
    int total = (N + 1) * 16;
    if (v >= total) return;
    int row = v >> 4;
    int cb = (v & 15) * 8;
    s16x8 o;
    if (row < N) {
        s16x8 zi = *(const s16x8*)(z + (size_t)row * 128 + cb);
#pragma unroll
        for (int j = 0; j < 8; ++j) {
            float x = bf2f((u16)zi[j]);
            float r = x * ss[cb + j] + ss[128 + cb + j];
            o[j] = (short)f2bf(r);
        }
    } else {
        o = (s16x8){0, 0, 0, 0, 0, 0, 0, 0};
    }
    *(s16x8*)(y + (size_t)row * 128 + cb) = o;
}

// ---- out = bn(z3) + bn(z4), f32 ----
__global__ void k_final(const u16* __restrict__ z3, const u16* __restrict__ z4,
                        const float* __restrict__ ssA, const float* __restrict__ ssB,
                        float* __restrict__ out, int N) {
    int v = blockIdx.x * 256 + threadIdx.x;
    int total = N * 32;
    if (v >= total) return;
    int row = v >> 5;
    int cb = (v & 31) * 4;
    s16x4 a = *(const s16x4*)(z3 + (size_t)row * 128 + cb);
    s16x4 b = *(const s16x4*)(z4 + (size_t)row * 128 + cb);
    f32x4 o;
#pragma unroll
    for (int j = 0; j < 4; ++j) {
        int c = cb + j;
        o[j] = bf2f((u16)a[j]) * ssA[c] + ssA[128 + c] +
               bf2f((u16)b[j]) * ssB[c] + ssB[128 + c];
    }
    *(f32x4*)(out + (size_t)row * 128 + cb) = o;
}

extern "C" void kernel_launch(void* const* d_in, const int* in_sizes, int n_in,
                              void* d_out, int out_size, void* d_ws, size_t ws_size,
                              hipStream_t stream) {
    const float* feat = (const float*)d_in[0];
    const int* nbr31 = (const int*)d_in[1];
    const int* nbr13 = (const int*)d_in[2];
    const float* W1 = (const float*)d_in[3];
    const float* W12 = (const float*)d_in[4];
    const float* W2 = (const float*)d_in[5];
    const float* W3 = (const float*)d_in[6];
    const float* g0 = (const float*)d_in[7];
    const float* b0 = (const float*)d_in[8];
    const float* g02 = (const float*)d_in[9];
    const float* b02 = (const float*)d_in[10];
    const float* g1 = (const float*)d_in[11];
    const float* b1 = (const float*)d_in[12];
    const float* g2 = (const float*)d_in[13];
    const float* b2 = (const float*)d_in[14];
    float* out = (float*)d_out;
    const int N = in_sizes[0] / 64;  // 200000

    char* p = (char*)d_ws;
    auto alloc = [&](size_t bytes) {
        char* r = p;
        p += (bytes + 255) & ~(size_t)255;
        return r;
    };
    float* stats = (float*)alloc(4 * 256 * sizeof(float));
    float* ss = (float*)alloc(4 * 256 * sizeof(float));
    u16* featbf = (u16*)alloc((size_t)(N + 1) * 64 * 2);
    u16* w1 = (u16*)alloc((size_t)9 * 64 * 128 * 2);
    u16* w2 = (u16*)alloc((size_t)9 * 64 * 128 * 2);
    u16* w12 = (u16*)alloc((size_t)9 * 128 * 128 * 2);
    u16* w3 = (u16*)alloc((size_t)9 * 128 * 128 * 2);
    u16* zA = (u16*)alloc((size_t)N * 128 * 2);
    u16* zB = (u16*)alloc((size_t)N * 128 * 2);
    u16* y1 = (u16*)alloc((size_t)(N + 1) * 128 * 2);
    u16* y2 = (u16*)alloc((size_t)(N + 1) * 128 * 2);

    hipMemsetAsync(stats, 0, 4 * 256 * sizeof(float), stream);

    int totF = (N + 1) * 64;
    k_feat2bf<<<(totF / 8 + 255) / 256, 256, 0, stream>>>(feat, featbf, totF, N * 64);
    k_swz<<<(9 * 64 * 128 + 255) / 256, 256, 0, stream>>>(W1, w1, 64);
    k_swz<<<(9 * 64 * 128 + 255) / 256, 256, 0, stream>>>(W2, w2, 64);
    k_swz<<<(9 * 128 * 128 + 255) / 256, 256, 0, stream>>>(W12, w12, 128);
    k_swz<<<(9 * 128 * 128 + 255) / 256, 256, 0, stream>>>(W3, w3, 128);

    int nblk = (N + 127) / 128;
    // shortcut: conv(nbr31, W1) ; main: conv(nbr13, W2)
    k_conv<64><<<nblk, 256, 0, stream>>>(featbf, nbr31, w1, zA, stats + 0, N);
    k_conv<64><<<nblk, 256, 0, stream>>>(featbf, nbr13, w2, zB, stats + 256, N);
    k_fin<<<1, 256, 0, stream>>>(stats, g0, b0, g1, b1, ss, N);
    int ablk = ((N + 1) * 16 + 255) / 256;
    k_aff<<<ablk, 256, 0, stream>>>(zA, ss + 0, y1, N);
    k_aff<<<ablk, 256, 0, stream>>>(zB, ss + 256, y2, N);
    // second stage: conv(y1, nbr13, W12) ; conv(y2, nbr31, W3)
    k_conv<128><<<nblk, 256, 0, stream>>>(y1, nbr13, w12, zA, stats + 512, N);
    k_conv<128><<<nblk, 256, 0, stream>>>(y2, nbr31, w3, zB, stats + 768, N);
    k_fin<<<1, 256, 0, stream>>>(stats + 512, g02, b02, g2, b2, ss + 512, N);
    k_final<<<(N * 32 + 255) / 256, 256, 0, stream>>>(zA, zB, ss + 512, ss + 768, out, N);
}

// Round 3
// 978.468 us; speedup vs baseline: 1.7442x; 1.3898x over previous
//
#include <hip/hip_runtime.h>
#include <hip/hip_bf16.h>

typedef unsigned short u16;
typedef unsigned int u32;
typedef __attribute__((ext_vector_type(8))) short s16x8;
typedef __attribute__((ext_vector_type(4))) short s16x4;
typedef __attribute__((ext_vector_type(4))) float f32x4;

__device__ inline u16 f2bf(float x) {
    u32 u = __float_as_uint(x);
    u32 r = (u + 0x7fffu + ((u >> 16) & 1u)) >> 16;
    return (u16)r;
}
__device__ inline float bf2f(u16 u) {
    return __uint_as_float(((u32)u) << 16);
}

// ---- features f32 -> bf16, with zero sentinel row at index N ----
__global__ void k_feat2bf(const float* __restrict__ f, u16* __restrict__ o,
                          int total, int nvalid) {
    int i = (blockIdx.x * 256 + threadIdx.x) * 8;
    if (i >= total) return;
    s16x8 v;
#pragma unroll
    for (int j = 0; j < 8; ++j) {
        float x = (i + j < nvalid) ? f[i + j] : 0.f;
        v[j] = (short)f2bf(x);
    }
    *(s16x8*)(o + i) = v;
}

// ---- weight swizzle: W[9][cin][128] f32 -> MFMA-B fragment-packed bf16 ----
// frag index fr = (tap*KC + kc)*8 + ct ; within frag: lane l holds 8 contiguous
// bf16 at fr*512 + l*8, element j = B[kc*32 + (l>>4)*8 + j][ct*16 + (l&15)]
__global__ void k_swz(const float* __restrict__ W, u16* __restrict__ o, int cin) {
    int i = blockIdx.x * 256 + threadIdx.x;
    int total = 9 * cin * 128;
    if (i >= total) return;
    int j = i & 7;
    int l = (i >> 3) & 63;
    int fr = i >> 9;
    int ct = fr & 7;
    int rest = fr >> 3;
    int kcn = cin >> 5;
    int kc = rest % kcn;
    int t = rest / kcn;
    int kk = kc * 32 + (l >> 4) * 8 + j;
    int c = ct * 16 + (l & 15);
    o[i] = f2bf(W[(t * cin + kk) * 128 + c]);
}

// ---- gather-conv: block = 512 thr (8 waves x 32 voxels), weights LDS-staged
// per tap, double-buffered. K = 9*CIN via 16x16x32 MFMA. Writes z = lrelu(conv)
// as bf16 [N][128], accumulates per-channel sum/sumsq into stats.
template <int CIN>
__global__ __launch_bounds__(512) void k_conv(
    const u16* __restrict__ src,   // (N+1) x CIN bf16, row N = zeros
    const int* __restrict__ nbr,   // 9 x N, sentinel = N
    const u16* __restrict__ w,     // fragment-packed weights
    u16* __restrict__ zout,        // N x 128 bf16
    float* __restrict__ stats,     // [256]: sum[128], sumsq[128]
    int N) {
    constexpr int KC = CIN / 32;        // 32-wide K chunks
    constexpr int TAPW = KC * 4096;     // u16 per tap chunk (KC*8 frags * 512)
    __shared__ u16 lds[2][TAPW];

    const int lane = threadIdx.x & 63;
    const int wv = threadIdx.x >> 6;    // 0..7
    const int base = blockIdx.x * 256 + wv * 32;
    const int am = lane & 15;
    const int grp = lane >> 4;
    const int vi0 = base + am;
    const int vi1 = base + 16 + am;
    const bool val0 = vi0 < N, val1 = vi1 < N;

    // prologue: nbr for tap 0; stage tap 0 into lds[0]
    int rn0 = val0 ? nbr[vi0] : N;
    int rn1 = val1 ? nbr[vi1] : N;
    s16x8 stg[KC];
    {
        const u16* gs = w + (size_t)(wv * KC) * 512 + lane * 8;
#pragma unroll
        for (int c = 0; c < KC; ++c) stg[c] = *(const s16x8*)(gs + c * 512);
#pragma unroll
        for (int c = 0; c < KC; ++c)
            *(s16x8*)&lds[0][(wv * KC + c) * 512 + lane * 8] = stg[c];
    }
    __syncthreads();

    f32x4 acc0[8], acc1[8];
#pragma unroll
    for (int ct = 0; ct < 8; ++ct) {
        acc0[ct] = (f32x4){0.f, 0.f, 0.f, 0.f};
        acc1[ct] = (f32x4){0.f, 0.f, 0.f, 0.f};
    }

    for (int t = 0; t < 9; ++t) {
        // A-gather bases for this tap (rn loaded one phase ago)
        const u16* sp0 = src + (size_t)rn0 * CIN + grp * 8;
        const u16* sp1 = src + (size_t)rn1 * CIN + grp * 8;

        // issue next-tap nbr loads + next-tap weight loads (consumed after compute)
        if (t < 8) {
            rn0 = val0 ? nbr[(t + 1) * N + vi0] : N;
            rn1 = val1 ? nbr[(t + 1) * N + vi1] : N;
            const u16* gs = w + (size_t)(t + 1) * TAPW + (size_t)(wv * KC) * 512 + lane * 8;
#pragma unroll
            for (int c = 0; c < KC; ++c) stg[c] = *(const s16x8*)(gs + c * 512);
        }

        // compute current tap from lds[t&1]
        const u16* lb = lds[t & 1];
#pragma unroll
        for (int kc = 0; kc < KC; ++kc) {
            s16x8 a0 = *(const s16x8*)(sp0 + kc * 32);
            s16x8 a1 = *(const s16x8*)(sp1 + kc * 32);
#pragma unroll
            for (int ct = 0; ct < 8; ++ct) {
                s16x8 b = *(const s16x8*)(lb + (kc * 8 + ct) * 512 + lane * 8);
                acc0[ct] = __builtin_amdgcn_mfma_f32_16x16x32_bf16(a0, b, acc0[ct], 0, 0, 0);
                acc1[ct] = __builtin_amdgcn_mfma_f32_16x16x32_bf16(a1, b, acc1[ct], 0, 0, 0);
            }
        }

        // write staged weights to the other buffer, then sync
        if (t < 8) {
            u16* ob = lds[(t & 1) ^ 1];
#pragma unroll
            for (int c = 0; c < KC; ++c)
                *(s16x8*)&ob[(wv * KC + c) * 512 + lane * 8] = stg[c];
        }
        __syncthreads();
    }

    // epilogue: lrelu, bf16 store, per-channel sum/sumsq
#pragma unroll
    for (int ct = 0; ct < 8; ++ct) {
        float s = 0.f, q = 0.f;
#pragma unroll
        for (int j = 0; j < 4; ++j) {
            {
                float x = acc0[ct][j];
                float z = (x > 0.f) ? x : 0.01f * x;
                int row = base + grp * 4 + j;
                if (row < N) zout[(size_t)row * 128 + ct * 16 + am] = f2bf(z);
                s += z;
                q += z * z;
            }
            {
                float x = acc1[ct][j];
                float z = (x > 0.f) ? x : 0.01f * x;
                int row = base + 16 + grp * 4 + j;
                if (row < N) zout[(size_t)row * 128 + ct * 16 + am] = f2bf(z);
                s += z;
                q += z * z;
            }
        }
        s += __shfl_xor(s, 16);
        q += __shfl_xor(q, 16);
        s += __shfl_xor(s, 32);
        q += __shfl_xor(q, 32);
        if (lane < 16) {
            atomicAdd(stats + ct * 16 + am, s);
            atomicAdd(stats + 128 + ct * 16 + am, q);
        }
    }
}

// ---- finalize two BN stat sets -> per-channel scale/shift ----
__global__ void k_fin(const float* __restrict__ stats,
                      const float* __restrict__ g0, const float* __restrict__ b0,
                      const float* __restrict__ g1, const float* __restrict__ b1,
                      float* __restrict__ ss, int N) {
    int tid = threadIdx.x;
    int set = tid >> 7, c = tid & 127;
    const float* st = stats + set * 256;
    float invN = 1.f / (float)N;
    float m = st[c] * invN;
    float var = st[128 + c] * invN - m * m;
    const float* g = set ? g1 : g0;
    const float* b = set ? b1 : b0;
    float sc = g[c] * rsqrtf(var + 1e-5f);
    float sh = b[c] - m * sc;
    float* o = ss + set * 256;
    o[c] = sc;
    o[128 + c] = sh;
}

// ---- y = z*scale + shift (bf16 out, with zero sentinel row N) ----
__global__ void k_aff(const u16* __restrict__ z, const float* __restrict__ ss,
                      u16* __restrict__ y, int N) {
    int v = blockIdx.x * 256 + threadIdx.x;
    int total = (N + 1) * 16;
    if (v >= total) return;
    int row = v >> 4;
    int cb = (v & 15) * 8;
    s16x8 o;
    if (row < N) {
        s16x8 zi = *(const s16x8*)(z + (size_t)row * 128 + cb);
#pragma unroll
        for (int j = 0; j < 8; ++j) {
            float x = bf2f((u16)zi[j]);
            float r = x * ss[cb + j] + ss[128 + cb + j];
            o[j] = (short)f2bf(r);
        }
    } else {
        o = (s16x8){0, 0, 0, 0, 0, 0, 0, 0};
    }
    *(s16x8*)(y + (size_t)row * 128 + cb) = o;
}

// ---- out = bn(z3) + bn(z4), f32 ----
__global__ void k_final(const u16* __restrict__ z3, const u16* __restrict__ z4,
                        const float* __restrict__ ssA, const float* __restrict__ ssB,
                        float* __restrict__ out, int N) {
    int v = blockIdx.x * 256 + threadIdx.x;
    int total = N * 32;
    if (v >= total) return;
    int row = v >> 5;
    int cb = (v & 31) * 4;
    s16x4 a = *(const s16x4*)(z3 + (size_t)row * 128 + cb);
    s16x4 b = *(const s16x4*)(z4 + (size_t)row * 128 + cb);
    f32x4 o;
#pragma unroll
    for (int j = 0; j < 4; ++j) {
        int c = cb + j;
        o[j] = bf2f((u16)a[j]) * ssA[c] + ssA[128 + c] +
               bf2f((u16)b[j]) * ssB[c] + ssB[128 + c];
    }
    *(f32x4*)(out + (size_t)row * 128 + cb) = o;
}

extern "C" void kernel_launch(void* const* d_in, const int* in_sizes, int n_in,
                              void* d_out, int out_size, void* d_ws, size_t ws_size,
                              hipStream_t stream) {
    const float* feat = (const float*)d_in[0];
    const int* nbr31 = (const int*)d_in[1];
    const int* nbr13 = (const int*)d_in[2];
    const float* W1 = (const float*)d_in[3];
    const float* W12 = (const float*)d_in[4];
    const float* W2 = (const float*)d_in[5];
    const float* W3 = (const float*)d_in[6];
    const float* g0 = (const float*)d_in[7];
    const float* b0 = (const float*)d_in[8];
    const float* g02 = (const float*)d_in[9];
    const float* b02 = (const float*)d_in[10];
    const float* g1 = (const float*)d_in[11];
    const float* b1 = (const float*)d_in[12];
    const float* g2 = (const float*)d_in[13];
    const float* b2 = (const float*)d_in[14];
    float* out = (float*)d_out;
    const int N = in_sizes[0] / 64;  // 200000

    char* p = (char*)d_ws;
    auto alloc = [&](size_t bytes) {
        char* r = p;
        p += (bytes + 255) & ~(size_t)255;
        return r;
    };
    float* stats = (float*)alloc(4 * 256 * sizeof(float));
    float* ss = (float*)alloc(4 * 256 * sizeof(float));
    u16* featbf = (u16*)alloc((size_t)(N + 1) * 64 * 2);
    u16* w1 = (u16*)alloc((size_t)9 * 64 * 128 * 2);
    u16* w2 = (u16*)alloc((size_t)9 * 64 * 128 * 2);
    u16* w12 = (u16*)alloc((size_t)9 * 128 * 128 * 2);
    u16* w3 = (u16*)alloc((size_t)9 * 128 * 128 * 2);
    u16* zA = (u16*)alloc((size_t)N * 128 * 2);
    u16* zB = (u16*)alloc((size_t)N * 128 * 2);
    u16* y1 = (u16*)alloc((size_t)(N + 1) * 128 * 2);
    u16* y2 = (u16*)alloc((size_t)(N + 1) * 128 * 2);

    hipMemsetAsync(stats, 0, 4 * 256 * sizeof(float), stream);

    int totF = (N + 1) * 64;
    k_feat2bf<<<(totF / 8 + 255) / 256, 256, 0, stream>>>(feat, featbf, totF, N * 64);
    k_swz<<<(9 * 64 * 128 + 255) / 256, 256, 0, stream>>>(W1, w1, 64);
    k_swz<<<(9 * 64 * 128 + 255) / 256, 256, 0, stream>>>(W2, w2, 64);
    k_swz<<<(9 * 128 * 128 + 255) / 256, 256, 0, stream>>>(W12, w12, 128);
    k_swz<<<(9 * 128 * 128 + 255) / 256, 256, 0, stream>>>(W3, w3, 128);

    int nblk = (N + 255) / 256;
    // shortcut: conv(nbr31, W1) ; main: conv(nbr13, W2)
    k_conv<64><<<nblk, 512, 0, stream>>>(featbf, nbr31, w1, zA, stats + 0, N);
    k_conv<64><<<nblk, 512, 0, stream>>>(featbf, nbr13, w2, zB, stats + 256, N);
    k_fin<<<1, 256, 0, stream>>>(stats, g0, b0, g1, b1, ss, N);
    int ablk = ((N + 1) * 16 + 255) / 256;
    k_aff<<<ablk, 256, 0, stream>>>(zA, ss + 0, y1, N);
    k_aff<<<ablk, 256, 0, stream>>>(zB, ss + 256, y2, N);
    // second stage: conv(y1, nbr13, W12) ; conv(y2, nbr31, W3)
    k_conv<128><<<nblk, 512, 0, stream>>>(y1, nbr13, w12, zA, stats + 512, N);
    k_conv<128><<<nblk, 512, 0, stream>>>(y2, nbr31, w3, zB, stats + 768, N);
    k_fin<<<1, 256, 0, stream>>>(stats + 512, g02, b02, g2, b2, ss + 512, N);
    k_final<<<(N * 32 + 255) / 256, 256, 0, stream>>>(zA, zB, ss + 512, ss + 768, out, N);
}

// Round 4
// 381.169 us; speedup vs baseline: 4.4774x; 2.5670x over previous
//
#include <hip/hip_runtime.h>
#include <hip/hip_bf16.h>

typedef unsigned short u16;
typedef unsigned int u32;
typedef __attribute__((ext_vector_type(8))) short s16x8;
typedef __attribute__((ext_vector_type(4))) short s16x4;
typedef __attribute__((ext_vector_type(4))) float f32x4;

__device__ inline u16 f2bf(float x) {
    u32 u = __float_as_uint(x);
    u32 r = (u + 0x7fffu + ((u >> 16) & 1u)) >> 16;
    return (u16)r;
}
__device__ inline float bf2f(u16 u) {
    return __uint_as_float(((u32)u) << 16);
}

// ---- features f32 -> bf16, with zero sentinel row at index N ----
__global__ void k_feat2bf(const float* __restrict__ f, u16* __restrict__ o,
                          int total, int nvalid) {
    int i = (blockIdx.x * 256 + threadIdx.x) * 8;
    if (i >= total) return;
    s16x8 v;
#pragma unroll
    for (int j = 0; j < 8; ++j) {
        float x = (i + j < nvalid) ? f[i + j] : 0.f;
        v[j] = (short)f2bf(x);
    }
    *(s16x8*)(o + i) = v;
}

// ---- weight swizzle: W[9][cin][128] f32 -> MFMA-B fragment-packed bf16 ----
// frag index fr = (tap*KC + kc)*8 + ct ; within frag: lane l holds 8 contiguous
// bf16 at fr*512 + l*8, element j = B[kc*32 + (l>>4)*8 + j][ct*16 + (l&15)]
__global__ void k_swz(const float* __restrict__ W, u16* __restrict__ o, int cin) {
    int i = blockIdx.x * 256 + threadIdx.x;
    int total = 9 * cin * 128;
    if (i >= total) return;
    int j = i & 7;
    int l = (i >> 3) & 63;
    int fr = i >> 9;
    int ct = fr & 7;
    int rest = fr >> 3;
    int kcn = cin >> 5;
    int kc = rest % kcn;
    int t = rest / kcn;
    int kk = kc * 32 + (l >> 4) * 8 + j;
    int c = ct * 16 + (l & 15);
    o[i] = f2bf(W[(t * cin + kk) * 128 + c]);
}

// ---- gather-conv: block = 1024 thr (16 waves x 32 voxels) x 64 output cols.
// blockIdx.y = column half. ALL taps' weights staged in LDS once (no loop
// barriers). Sentinel-aware tap skipping per 16-row group. Per-block stats
// reduction in LDS, then 64 global atomics.
template <int CIN>
__global__ __launch_bounds__(1024) void k_conv(
    const u16* __restrict__ src,   // (N+1) x CIN bf16, row N = zeros
    const int* __restrict__ nbr,   // 9 x N, sentinel = N
    const u16* __restrict__ w,     // fragment-packed weights (full 128 cols)
    u16* __restrict__ zout,        // N x 128 bf16
    float* __restrict__ stats,     // [256]: sum[128], sumsq[128]
    int N) {
    constexpr int KC = CIN / 32;      // 32-wide K chunks
    constexpr int FR = 9 * KC * 4;    // frags resident (4 col-tiles)
    __shared__ u16 wl[FR * 512];
    __shared__ float sstat[128];

    const int tid = threadIdx.x;
    const int half = blockIdx.y;

    // stage this half's weights for all taps; zero stats
    for (int i = tid; i < FR * 64; i += 1024) {
        int p = i & 63;       // 16B piece within frag
        int f = i >> 6;       // ((t*KC+kc)*4 + ct')
        int ctp = f & 3;
        int tk = f >> 2;
        s16x8 v = *(const s16x8*)(w + ((size_t)(tk * 8 + half * 4 + ctp)) * 512 + p * 8);
        *(s16x8*)&wl[(size_t)f * 512 + p * 8] = v;
    }
    if (tid < 128) sstat[tid] = 0.f;
    __syncthreads();

    const int lane = tid & 63;
    const int wv = tid >> 6;          // 0..15
    const int base = blockIdx.x * 512 + wv * 32;
    const int am = lane & 15;
    const int grp = lane >> 4;
    const int vi0 = base + am;
    const int vi1 = base + 16 + am;

    int rn0[9], rn1[9];
#pragma unroll
    for (int t = 0; t < 9; ++t) {
        rn0[t] = (vi0 < N) ? nbr[t * N + vi0] : N;
        rn1[t] = (vi1 < N) ? nbr[t * N + vi1] : N;
    }

    f32x4 acc0[4], acc1[4];
#pragma unroll
    for (int c = 0; c < 4; ++c) {
        acc0[c] = (f32x4){0.f, 0.f, 0.f, 0.f};
        acc1[c] = (f32x4){0.f, 0.f, 0.f, 0.f};
    }

#pragma unroll
    for (int t = 0; t < 9; ++t) {
        const u16* lb = wl + (size_t)t * (KC * 4) * 512 + lane * 8;
        if (__any(rn0[t] != N)) {
            const u16* sp = src + (size_t)rn0[t] * CIN + grp * 8;
#pragma unroll
            for (int kc = 0; kc < KC; ++kc) {
                s16x8 a = *(const s16x8*)(sp + kc * 32);
#pragma unroll
                for (int c = 0; c < 4; ++c) {
                    s16x8 b = *(const s16x8*)(lb + (kc * 4 + c) * 512);
                    acc0[c] = __builtin_amdgcn_mfma_f32_16x16x32_bf16(a, b, acc0[c], 0, 0, 0);
                }
            }
        }
        if (__any(rn1[t] != N)) {
            const u16* sp = src + (size_t)rn1[t] * CIN + grp * 8;
#pragma unroll
            for (int kc = 0; kc < KC; ++kc) {
                s16x8 a = *(const s16x8*)(sp + kc * 32);
#pragma unroll
                for (int c = 0; c < 4; ++c) {
                    s16x8 b = *(const s16x8*)(lb + (kc * 4 + c) * 512);
                    acc1[c] = __builtin_amdgcn_mfma_f32_16x16x32_bf16(a, b, acc1[c], 0, 0, 0);
                }
            }
        }
    }

    // epilogue: lrelu, bf16 store, block-local stats
#pragma unroll
    for (int c = 0; c < 4; ++c) {
        float s = 0.f, q = 0.f;
        const int col = half * 64 + c * 16 + am;
#pragma unroll
        for (int j = 0; j < 4; ++j) {
            {
                float x = acc0[c][j];
                float z = (x > 0.f) ? x : 0.01f * x;
                int row = base + grp * 4 + j;
                if (row < N) zout[(size_t)row * 128 + col] = f2bf(z);
                s += z;
                q += z * z;
            }
            {
                float x = acc1[c][j];
                float z = (x > 0.f) ? x : 0.01f * x;
                int row = base + 16 + grp * 4 + j;
                if (row < N) zout[(size_t)row * 128 + col] = f2bf(z);
                s += z;
                q += z * z;
            }
        }
        s += __shfl_xor(s, 16);
        q += __shfl_xor(q, 16);
        s += __shfl_xor(s, 32);
        q += __shfl_xor(q, 32);
        if (lane < 16) {
            atomicAdd(&sstat[c * 16 + am], s);
            atomicAdd(&sstat[64 + c * 16 + am], q);
        }
    }
    __syncthreads();
    if (tid < 64) {
        int cg = half * 64 + tid;
        atomicAdd(stats + cg, sstat[tid]);
        atomicAdd(stats + 128 + cg, sstat[64 + tid]);
    }
}

// ---- finalize two BN stat sets -> per-channel scale/shift ----
__global__ void k_fin(const float* __restrict__ stats,
                      const float* __restrict__ g0, const float* __restrict__ b0,
                      const float* __restrict__ g1, const float* __restrict__ b1,
                      float* __restrict__ ss, int N) {
    int tid = threadIdx.x;
    int set = tid >> 7, c = tid & 127;
    const float* st = stats + set * 256;
    float invN = 1.f / (float)N;
    float m = st[c] * invN;
    float var = st[128 + c] * invN - m * m;
    const float* g = set ? g1 : g0;
    const float* b = set ? b1 : b0;
    float sc = g[c] * rsqrtf(var + 1e-5f);
    float sh = b[c] - m * sc;
    float* o = ss + set * 256;
    o[c] = sc;
    o[128 + c] = sh;
}

// ---- y = z*scale + shift (bf16 out, with zero sentinel row N) ----
__global__ void k_aff(const u16* __restrict__ z, const float* __restrict__ ss,
                      u16* __restrict__ y, int N) {
    int v = blockIdx.x * 256 + threadIdx.x;
    int total = (N + 1) * 16;
    if (v >= total) return;
    int row = v >> 4;
    int cb = (v & 15) * 8;
    s16x8 o;
    if (row < N) {
        s16x8 zi = *(const s16x8*)(z + (size_t)row * 128 + cb);
#pragma unroll
        for (int j = 0; j < 8; ++j) {
            float x = bf2f((u16)zi[j]);
            float r = x * ss[cb + j] + ss[128 + cb + j];
            o[j] = (short)f2bf(r);
        }
    } else {
        o = (s16x8){0, 0, 0, 0, 0, 0, 0, 0};
    }
    *(s16x8*)(y + (size_t)row * 128 + cb) = o;
}

// ---- out = bn(z3) + bn(z4), f32 ----
__global__ void k_final(const u16* __restrict__ z3, const u16* __restrict__ z4,
                        const float* __restrict__ ssA, const float* __restrict__ ssB,
                        float* __restrict__ out, int N) {
    int v = blockIdx.x * 256 + threadIdx.x;
    int total = N * 32;
    if (v >= total) return;
    int row = v >> 5;
    int cb = (v & 31) * 4;
    s16x4 a = *(const s16x4*)(z3 + (size_t)row * 128 + cb);
    s16x4 b = *(const s16x4*)(z4 + (size_t)row * 128 + cb);
    f32x4 o;
#pragma unroll
    for (int j = 0; j < 4; ++j) {
        int c = cb + j;
        o[j] = bf2f((u16)a[j]) * ssA[c] + ssA[128 + c] +
               bf2f((u16)b[j]) * ssB[c] + ssB[128 + c];
    }
    *(f32x4*)(out + (size_t)row * 128 + cb) = o;
}

extern "C" void kernel_launch(void* const* d_in, const int* in_sizes, int n_in,
                              void* d_out, int out_size, void* d_ws, size_t ws_size,
                              hipStream_t stream) {
    const float* feat = (const float*)d_in[0];
    const int* nbr31 = (const int*)d_in[1];
    const int* nbr13 = (const int*)d_in[2];
    const float* W1 = (const float*)d_in[3];
    const float* W12 = (const float*)d_in[4];
    const float* W2 = (const float*)d_in[5];
    const float* W3 = (const float*)d_in[6];
    const float* g0 = (const float*)d_in[7];
    const float* b0 = (const float*)d_in[8];
    const float* g02 = (const float*)d_in[9];
    const float* b02 = (const float*)d_in[10];
    const float* g1 = (const float*)d_in[11];
    const float* b1 = (const float*)d_in[12];
    const float* g2 = (const float*)d_in[13];
    const float* b2 = (const float*)d_in[14];
    float* out = (float*)d_out;
    const int N = in_sizes[0] / 64;  // 200000

    char* p = (char*)d_ws;
    auto alloc = [&](size_t bytes) {
        char* r = p;
        p += (bytes + 255) & ~(size_t)255;
        return r;
    };
    float* stats = (float*)alloc(4 * 256 * sizeof(float));
    float* ss = (float*)alloc(4 * 256 * sizeof(float));
    u16* featbf = (u16*)alloc((size_t)(N + 1) * 64 * 2);
    u16* w1 = (u16*)alloc((size_t)9 * 64 * 128 * 2);
    u16* w2 = (u16*)alloc((size_t)9 * 64 * 128 * 2);
    u16* w12 = (u16*)alloc((size_t)9 * 128 * 128 * 2);
    u16* w3 = (u16*)alloc((size_t)9 * 128 * 128 * 2);
    u16* zA = (u16*)alloc((size_t)N * 128 * 2);
    u16* zB = (u16*)alloc((size_t)N * 128 * 2);
    u16* y1 = (u16*)alloc((size_t)(N + 1) * 128 * 2);
    u16* y2 = (u16*)alloc((size_t)(N + 1) * 128 * 2);

    hipMemsetAsync(stats, 0, 4 * 256 * sizeof(float), stream);

    int totF = (N + 1) * 64;
    k_feat2bf<<<(totF / 8 + 255) / 256, 256, 0, stream>>>(feat, featbf, totF, N * 64);
    k_swz<<<(9 * 64 * 128 + 255) / 256, 256, 0, stream>>>(W1, w1, 64);
    k_swz<<<(9 * 64 * 128 + 255) / 256, 256, 0, stream>>>(W2, w2, 64);
    k_swz<<<(9 * 128 * 128 + 255) / 256, 256, 0, stream>>>(W12, w12, 128);
    k_swz<<<(9 * 128 * 128 + 255) / 256, 256, 0, stream>>>(W3, w3, 128);

    dim3 cgrid((N + 511) / 512, 2);
    // shortcut: conv(nbr31, W1) ; main: conv(nbr13, W2)
    k_conv<64><<<cgrid, 1024, 0, stream>>>(featbf, nbr31, w1, zA, stats + 0, N);
    k_conv<64><<<cgrid, 1024, 0, stream>>>(featbf, nbr13, w2, zB, stats + 256, N);
    k_fin<<<1, 256, 0, stream>>>(stats, g0, b0, g1, b1, ss, N);
    int ablk = ((N + 1) * 16 + 255) / 256;
    k_aff<<<ablk, 256, 0, stream>>>(zA, ss + 0, y1, N);
    k_aff<<<ablk, 256, 0, stream>>>(zB, ss + 256, y2, N);
    // second stage: conv(y1, nbr13, W12) ; conv(y2, nbr31, W3)
    k_conv<128><<<cgrid, 1024, 0, stream>>>(y1, nbr13, w12, zA, stats + 512, N);
    k_conv<128><<<cgrid, 1024, 0, stream>>>(y2, nbr31, w3, zB, stats + 768, N);
    k_fin<<<1, 256, 0, stream>>>(stats + 512, g02, b02, g2, b2, ss + 512, N);
    k_final<<<(N * 32 + 255) / 256, 256, 0, stream>>>(zA, zB, ss + 512, ss + 768, out, N);
}